// Round 1
// baseline (429.269 us; speedup 1.0000x reference)
//
#include <hip/hip_runtime.h>
#include <hip/hip_bf16.h>
#include <stdint.h>

#define SEQ 4096
#define DIM 1024
#define NHEADS 16
#define DHEAD 64
#define INNER 1024

typedef __hip_bfloat16 bf16;
typedef __attribute__((ext_vector_type(8))) short short8;
typedef __attribute__((ext_vector_type(4))) float floatx4;

__device__ __forceinline__ unsigned short f2bf_bits(float f) {
    bf16 h = __float2bfloat16(f);
    return *reinterpret_cast<unsigned short*>(&h);
}

// ---------------- convert x (fp32 -> bf16), 4 elems/thread ----------------
__global__ __launch_bounds__(256) void convert_x_kernel(const float* __restrict__ x,
                                                        bf16* __restrict__ xb) {
    int i = (blockIdx.x * 256 + threadIdx.x) * 4;
    float4 f = *reinterpret_cast<const float4*>(x + i);
    unsigned long long p = (unsigned long long)f2bf_bits(f.x)
                         | ((unsigned long long)f2bf_bits(f.y) << 16)
                         | ((unsigned long long)f2bf_bits(f.z) << 32)
                         | ((unsigned long long)f2bf_bits(f.w) << 48);
    *reinterpret_cast<unsigned long long*>(xb + i) = p;
}

// ------------- transpose + convert weights: W[k][n] -> Wt[n][k] bf16 -------------
__global__ __launch_bounds__(256) void transpose_w_kernel(
        const float* __restrict__ W0, const float* __restrict__ W1,
        const float* __restrict__ W2, const float* __restrict__ W3,
        bf16* __restrict__ T0, bf16* __restrict__ T1,
        bf16* __restrict__ T2, bf16* __restrict__ T3) {
    const float* W; bf16* T;
    switch (blockIdx.z) {
        case 0:  W = W0; T = T0; break;
        case 1:  W = W1; T = T1; break;
        case 2:  W = W2; T = T2; break;
        default: W = W3; T = T3; break;
    }
    __shared__ float tile[32][33];
    int k0 = blockIdx.x * 32, n0 = blockIdx.y * 32;
    int tx = threadIdx.x, ty = threadIdx.y;
    #pragma unroll
    for (int i = 0; i < 4; i++)
        tile[ty + 8 * i][tx] = W[(size_t)(k0 + ty + 8 * i) * 1024 + n0 + tx];
    __syncthreads();
    #pragma unroll
    for (int i = 0; i < 4; i++)
        T[(size_t)(n0 + ty + 8 * i) * 1024 + k0 + tx] = __float2bfloat16(tile[tx][ty + 8 * i]);
}

// ---------------- 128x128 bf16 MFMA GEMM tile body (K=1024) ----------------
// A: [M][1024] row-major bf16.  Bt: [N][1024] row-major bf16 (i.e. B transposed,
// k-contiguous).  Each block: 4 waves, wave -> 64x64 subtile -> 4x4 16x16 accs.
__device__ __forceinline__ void gemm128_body(const bf16* __restrict__ A,
                                             const bf16* __restrict__ Bt,
                                             int m0, int n0, floatx4 acc[4][4]) {
    __shared__ __align__(16) bf16 As[128][72];
    __shared__ __align__(16) bf16 Bs[128][72];
    const int tid = threadIdx.x;
    const int wave = tid >> 6;
    const int lane = tid & 63;
    const int l15 = lane & 15;
    const int quad = lane >> 4;
    const int wm = (wave >> 1) * 64;
    const int wn = (wave & 1) * 64;

    #pragma unroll
    for (int i = 0; i < 4; i++)
        #pragma unroll
        for (int j = 0; j < 4; j++)
            acc[i][j] = (floatx4){0.f, 0.f, 0.f, 0.f};

    for (int k0 = 0; k0 < 1024; k0 += 64) {
        __syncthreads();
        // stage A tile 128x64 and B tile 128(n)x64(k): 1024 units of 8 bf16 each
        #pragma unroll
        for (int r = 0; r < 4; r++) {
            int u = tid + 256 * r;
            int kg = u & 7, m = u >> 3;
            *reinterpret_cast<short8*>(&As[m][kg * 8]) =
                *reinterpret_cast<const short8*>(A + (size_t)(m0 + m) * 1024 + k0 + kg * 8);
            int n = u & 127, kg2 = u >> 7;
            *reinterpret_cast<short8*>(&Bs[n][kg2 * 8]) =
                *reinterpret_cast<const short8*>(Bt + (size_t)(n0 + n) * 1024 + k0 + kg2 * 8);
        }
        __syncthreads();
        #pragma unroll
        for (int ks = 0; ks < 2; ks++) {
            short8 af[4], bfr[4];
            #pragma unroll
            for (int i = 0; i < 4; i++)
                af[i] = *reinterpret_cast<const short8*>(&As[wm + i * 16 + l15][ks * 32 + quad * 8]);
            #pragma unroll
            for (int j = 0; j < 4; j++)
                bfr[j] = *reinterpret_cast<const short8*>(&Bs[wn + j * 16 + l15][ks * 32 + quad * 8]);
            #pragma unroll
            for (int i = 0; i < 4; i++)
                #pragma unroll
                for (int j = 0; j < 4; j++)
                    acc[i][j] = __builtin_amdgcn_mfma_f32_16x16x32_bf16(af[i], bfr[j], acc[i][j], 0, 0, 0);
        }
    }
}

// ---------------- QKV projection: z selects Wq/Wk/Wv; writes head-major bf16 ----------------
__global__ __launch_bounds__(256) void qkv_gemm_kernel(
        const bf16* __restrict__ xb,
        const bf16* __restrict__ Wqt, const bf16* __restrict__ Wkt, const bf16* __restrict__ Wvt,
        bf16* __restrict__ Qh, bf16* __restrict__ Kh, bf16* __restrict__ Vh) {
    const bf16* Bt; bf16* O; float scale = 1.0f;
    if (blockIdx.z == 0)      { Bt = Wqt; O = Qh; scale = 0.125f; }  // beta = 1/sqrt(64)
    else if (blockIdx.z == 1) { Bt = Wkt; O = Kh; }
    else                      { Bt = Wvt; O = Vh; }
    int n0 = blockIdx.x * 128, m0 = blockIdx.y * 128;
    floatx4 acc[4][4];
    gemm128_body(xb, Bt, m0, n0, acc);

    const int tid = threadIdx.x, wave = tid >> 6, lane = tid & 63;
    const int l15 = lane & 15, quad = lane >> 4;
    const int wm = (wave >> 1) * 64, wn = (wave & 1) * 64;
    #pragma unroll
    for (int i = 0; i < 4; i++)
        #pragma unroll
        for (int j = 0; j < 4; j++) {
            int col = n0 + wn + j * 16 + l15;   // inner index
            int h = col >> 6, d = col & 63;
            #pragma unroll
            for (int r = 0; r < 4; r++) {
                int row = m0 + wm + i * 16 + quad * 4 + r;  // C/D: row = quad*4+reg
                O[((size_t)h * SEQ + row) * DHEAD + d] = __float2bfloat16(acc[i][j][r] * scale);
            }
        }
}

// ---------------- output projection: out = Oa @ Wo + bo (fp32 out) ----------------
__global__ __launch_bounds__(256) void out_gemm_kernel(
        const bf16* __restrict__ Oa, const bf16* __restrict__ Wot,
        const float* __restrict__ bo, float* __restrict__ out) {
    int n0 = blockIdx.x * 128, m0 = blockIdx.y * 128;
    floatx4 acc[4][4];
    gemm128_body(Oa, Wot, m0, n0, acc);

    const int tid = threadIdx.x, wave = tid >> 6, lane = tid & 63;
    const int l15 = lane & 15, quad = lane >> 4;
    const int wm = (wave >> 1) * 64, wn = (wave & 1) * 64;
    #pragma unroll
    for (int i = 0; i < 4; i++)
        #pragma unroll
        for (int j = 0; j < 4; j++) {
            int col = n0 + wn + j * 16 + l15;
            float b = bo[col];
            #pragma unroll
            for (int r = 0; r < 4; r++) {
                int row = m0 + wm + i * 16 + quad * 4 + r;
                out[(size_t)row * DIM + col] = acc[i][j][r] + b;
            }
        }
}

// ---------------- causal flash attention: 1 block = 1 head x 64 q-rows ----------------
__global__ __launch_bounds__(256) void attention_kernel(
        const bf16* __restrict__ Qh, const bf16* __restrict__ Kh,
        const bf16* __restrict__ Vh, bf16* __restrict__ Oa) {
    __shared__ __align__(16) bf16 Ks[64][72];      // [key][d]
    __shared__ __align__(16) bf16 Vts[64][72];     // [d][key]  (V transposed)
    __shared__ __align__(16) bf16 Ps[4][16][72];   // per-wave P: [q][key]
    const int tid = threadIdx.x, wave = tid >> 6, lane = tid & 63;
    const int l15 = lane & 15, quad = lane >> 4;
    const int head = blockIdx.y;
    const int qbase = blockIdx.x * 64;
    const size_t headoff = (size_t)head * SEQ * DHEAD;

    // Q A-fragments (q already scaled by beta): row = lane&15, k along d
    const int qr = qbase + wave * 16 + l15;
    short8 aq[2];
    #pragma unroll
    for (int s = 0; s < 2; s++)
        aq[s] = *reinterpret_cast<const short8*>(Qh + headoff + (size_t)qr * DHEAD + s * 32 + quad * 8);

    floatx4 acc_o[4];
    #pragma unroll
    for (int c = 0; c < 4; c++) acc_o[c] = (floatx4){0.f, 0.f, 0.f, 0.f};
    float m_run[4], l_run[4];
    #pragma unroll
    for (int r = 0; r < 4; r++) { m_run[r] = -1e30f; l_run[r] = 0.f; }

    const float LOG2E = 1.4426950408889634f;
    const int ntiles = blockIdx.x + 1;   // causal: key tiles 0..qtile
    for (int kt = 0; kt < ntiles; kt++) {
        const int kbase = kt * 64;
        __syncthreads();   // protect Ks/Vts (and prior-iter Ps reads finished in-wave)
        #pragma unroll
        for (int r = 0; r < 2; r++) {
            int u = tid + 256 * r;
            // K: unit (key, dg) -> contiguous 16B load + b128 LDS write
            int dg = u & 7, key = u >> 3;
            *reinterpret_cast<short8*>(&Ks[key][dg * 8]) =
                *reinterpret_cast<const short8*>(Kh + headoff + (size_t)(kbase + key) * DHEAD + dg * 8);
            // V transposed: unit (d, kg): 8 strided loads (coalesced across lanes), b128 write
            int d = u & 63, kg = u >> 6;
            short8 v;
            #pragma unroll
            for (int j = 0; j < 8; j++)
                v[j] = reinterpret_cast<const short*>(Vh)[headoff + (size_t)(kbase + kg * 8 + j) * DHEAD + d];
            *reinterpret_cast<short8*>(&Vts[d][kg * 8]) = v;
        }
        __syncthreads();

        // S = Q K^T  (16q x 64key per wave)
        floatx4 acc_s[4];
        #pragma unroll
        for (int c = 0; c < 4; c++) acc_s[c] = (floatx4){0.f, 0.f, 0.f, 0.f};
        #pragma unroll
        for (int c = 0; c < 4; c++)
            #pragma unroll
            for (int s = 0; s < 2; s++) {
                short8 bk = *reinterpret_cast<const short8*>(&Ks[c * 16 + l15][s * 32 + quad * 8]);
                acc_s[c] = __builtin_amdgcn_mfma_f32_16x16x32_bf16(aq[s], bk, acc_s[c], 0, 0, 0);
            }
        // causal mask (C/D layout: row=quad*4+r, col=lane&15)
        #pragma unroll
        for (int c = 0; c < 4; c++) {
            int kj = kbase + c * 16 + l15;
            #pragma unroll
            for (int r = 0; r < 4; r++) {
                int qi = qbase + wave * 16 + quad * 4 + r;
                if (kj > qi) acc_s[c][r] = -1e30f;
            }
        }
        // online softmax per q-row
        float p[4][4];
        #pragma unroll
        for (int r = 0; r < 4; r++) {
            float mx = fmaxf(fmaxf(acc_s[0][r], acc_s[1][r]), fmaxf(acc_s[2][r], acc_s[3][r]));
            #pragma unroll
            for (int off = 1; off < 16; off <<= 1)
                mx = fmaxf(mx, __shfl_xor(mx, off, 16));
            float mnew = fmaxf(m_run[r], mx);
            float alpha = exp2f((m_run[r] - mnew) * LOG2E);
            m_run[r] = mnew;
            float rs = 0.f;
            #pragma unroll
            for (int c = 0; c < 4; c++) {
                float pv = exp2f((acc_s[c][r] - mnew) * LOG2E);
                p[c][r] = pv;
                rs += pv;
            }
            #pragma unroll
            for (int off = 1; off < 16; off <<= 1)
                rs += __shfl_xor(rs, off, 16);
            l_run[r] = l_run[r] * alpha + rs;
            #pragma unroll
            for (int c = 0; c < 4; c++) acc_o[c][r] *= alpha;
        }
        // P: C/D layout -> LDS -> A-operand layout
        #pragma unroll
        for (int c = 0; c < 4; c++)
            #pragma unroll
            for (int r = 0; r < 4; r++)
                Ps[wave][quad * 4 + r][c * 16 + l15] = __float2bfloat16(p[c][r]);
        __syncthreads();
        // O += P V
        #pragma unroll
        for (int c = 0; c < 4; c++)
            #pragma unroll
            for (int s = 0; s < 2; s++) {
                short8 ap = *reinterpret_cast<const short8*>(&Ps[wave][l15][s * 32 + quad * 8]);
                short8 bv = *reinterpret_cast<const short8*>(&Vts[c * 16 + l15][s * 32 + quad * 8]);
                acc_o[c] = __builtin_amdgcn_mfma_f32_16x16x32_bf16(ap, bv, acc_o[c], 0, 0, 0);
            }
    }
    // write O (row-major [SEQ][INNER] bf16), normalized
    #pragma unroll
    for (int c = 0; c < 4; c++) {
        int col = head * DHEAD + c * 16 + l15;
        #pragma unroll
        for (int r = 0; r < 4; r++) {
            int qi = qbase + wave * 16 + quad * 4 + r;
            Oa[(size_t)qi * INNER + col] = __float2bfloat16(acc_o[c][r] / l_run[r]);
        }
    }
}

extern "C" void kernel_launch(void* const* d_in, const int* in_sizes, int n_in,
                              void* d_out, int out_size, void* d_ws, size_t ws_size,
                              hipStream_t stream) {
    const float* x  = (const float*)d_in[0];
    const float* Wq = (const float*)d_in[1];
    const float* Wk = (const float*)d_in[2];
    const float* Wv = (const float*)d_in[3];
    const float* Wo = (const float*)d_in[4];
    const float* bo = (const float*)d_in[5];
    float* out = (float*)d_out;

    char* ws = (char*)d_ws;
    size_t off = 0;
    bf16* xb  = (bf16*)(ws + off); off += (size_t)SEQ * DIM * 2;
    bf16* Wqt = (bf16*)(ws + off); off += (size_t)DIM * INNER * 2;
    bf16* Wkt = (bf16*)(ws + off); off += (size_t)DIM * INNER * 2;
    bf16* Wvt = (bf16*)(ws + off); off += (size_t)DIM * INNER * 2;
    bf16* Wot = (bf16*)(ws + off); off += (size_t)INNER * DIM * 2;
    bf16* Qh  = (bf16*)(ws + off); off += (size_t)NHEADS * SEQ * DHEAD * 2;
    bf16* Kh  = (bf16*)(ws + off); off += (size_t)NHEADS * SEQ * DHEAD * 2;
    bf16* Vh  = (bf16*)(ws + off); off += (size_t)NHEADS * SEQ * DHEAD * 2;
    bf16* Oa  = (bf16*)(ws + off); off += (size_t)SEQ * INNER * 2;  // ~48 MB total

    convert_x_kernel<<<(SEQ * DIM) / 1024, 256, 0, stream>>>(x, xb);
    transpose_w_kernel<<<dim3(32, 32, 4), dim3(32, 8), 0, stream>>>(Wq, Wk, Wv, Wo,
                                                                    Wqt, Wkt, Wvt, Wot);
    qkv_gemm_kernel<<<dim3(8, 32, 3), 256, 0, stream>>>(xb, Wqt, Wkt, Wvt, Qh, Kh, Vh);
    attention_kernel<<<dim3(64, 16), 256, 0, stream>>>(Qh, Kh, Vh, Oa);
    out_gemm_kernel<<<dim3(8, 32), 256, 0, stream>>>(Oa, Wot, bo, out);
}

// Round 2
// 360.337 us; speedup vs baseline: 1.1913x; 1.1913x over previous
//
#include <hip/hip_runtime.h>
#include <hip/hip_bf16.h>
#include <stdint.h>

#define SEQ 4096
#define DIM 1024
#define NHEADS 16
#define DHEAD 64
#define INNER 1024

typedef __hip_bfloat16 bf16;
typedef __attribute__((ext_vector_type(8))) short short8;
typedef __attribute__((ext_vector_type(4))) float floatx4;

__device__ __forceinline__ unsigned short f2bf_bits(float f) {
    bf16 h = __float2bfloat16(f);
    return *reinterpret_cast<unsigned short*>(&h);
}

// ---------------- convert x (fp32 -> bf16), 4 elems/thread ----------------
__global__ __launch_bounds__(256) void convert_x_kernel(const float* __restrict__ x,
                                                        bf16* __restrict__ xb) {
    int i = (blockIdx.x * 256 + threadIdx.x) * 4;
    float4 f = *reinterpret_cast<const float4*>(x + i);
    unsigned long long p = (unsigned long long)f2bf_bits(f.x)
                         | ((unsigned long long)f2bf_bits(f.y) << 16)
                         | ((unsigned long long)f2bf_bits(f.z) << 32)
                         | ((unsigned long long)f2bf_bits(f.w) << 48);
    *reinterpret_cast<unsigned long long*>(xb + i) = p;
}

// ------------- transpose + convert weights: W[k][n] -> Wt[n][k] bf16 -------------
__global__ __launch_bounds__(256) void transpose_w_kernel(
        const float* __restrict__ W0, const float* __restrict__ W1,
        const float* __restrict__ W2, const float* __restrict__ W3,
        bf16* __restrict__ T0, bf16* __restrict__ T1,
        bf16* __restrict__ T2, bf16* __restrict__ T3) {
    const float* W; bf16* T;
    switch (blockIdx.z) {
        case 0:  W = W0; T = T0; break;
        case 1:  W = W1; T = T1; break;
        case 2:  W = W2; T = T2; break;
        default: W = W3; T = T3; break;
    }
    __shared__ float tile[32][33];
    int k0 = blockIdx.x * 32, n0 = blockIdx.y * 32;
    int tx = threadIdx.x, ty = threadIdx.y;
    #pragma unroll
    for (int i = 0; i < 4; i++)
        tile[ty + 8 * i][tx] = W[(size_t)(k0 + ty + 8 * i) * 1024 + n0 + tx];
    __syncthreads();
    #pragma unroll
    for (int i = 0; i < 4; i++)
        T[(size_t)(n0 + ty + 8 * i) * 1024 + k0 + tx] = __float2bfloat16(tile[tx][ty + 8 * i]);
}

// ------------- transpose V: Vh[h][n][d] -> Vt[h][d][n] (bf16) -------------
__global__ __launch_bounds__(256) void transpose_v_kernel(const bf16* __restrict__ Vh,
                                                          bf16* __restrict__ Vt) {
    __shared__ bf16 tile[32][33];
    int h = blockIdx.z;
    int n0 = blockIdx.x * 32, d0 = blockIdx.y * 32;
    int tx = threadIdx.x, ty = threadIdx.y;
    const bf16* src = Vh + (size_t)h * SEQ * DHEAD;
    bf16* dst = Vt + (size_t)h * DHEAD * SEQ;
    #pragma unroll
    for (int i = 0; i < 4; i++)
        tile[ty + 8 * i][tx] = src[(size_t)(n0 + ty + 8 * i) * DHEAD + d0 + tx];
    __syncthreads();
    #pragma unroll
    for (int i = 0; i < 4; i++)
        dst[(size_t)(d0 + ty + 8 * i) * SEQ + n0 + tx] = tile[tx][ty + 8 * i];
}

// ---------------- 128x128 bf16 MFMA GEMM tile body (K=1024) ----------------
__device__ __forceinline__ void gemm128_body(const bf16* __restrict__ A,
                                             const bf16* __restrict__ Bt,
                                             int m0, int n0, floatx4 acc[4][4]) {
    __shared__ __align__(16) bf16 As[128][72];
    __shared__ __align__(16) bf16 Bs[128][72];
    const int tid = threadIdx.x;
    const int wave = tid >> 6;
    const int lane = tid & 63;
    const int l15 = lane & 15;
    const int quad = lane >> 4;
    const int wm = (wave >> 1) * 64;
    const int wn = (wave & 1) * 64;

    #pragma unroll
    for (int i = 0; i < 4; i++)
        #pragma unroll
        for (int j = 0; j < 4; j++)
            acc[i][j] = (floatx4){0.f, 0.f, 0.f, 0.f};

    for (int k0 = 0; k0 < 1024; k0 += 64) {
        __syncthreads();
        #pragma unroll
        for (int r = 0; r < 4; r++) {
            int u = tid + 256 * r;
            int kg = u & 7, m = u >> 3;
            *reinterpret_cast<short8*>(&As[m][kg * 8]) =
                *reinterpret_cast<const short8*>(A + (size_t)(m0 + m) * 1024 + k0 + kg * 8);
            int n = u & 127, kg2 = u >> 7;
            *reinterpret_cast<short8*>(&Bs[n][kg2 * 8]) =
                *reinterpret_cast<const short8*>(Bt + (size_t)(n0 + n) * 1024 + k0 + kg2 * 8);
        }
        __syncthreads();
        #pragma unroll
        for (int ks = 0; ks < 2; ks++) {
            short8 af[4], bfr[4];
            #pragma unroll
            for (int i = 0; i < 4; i++)
                af[i] = *reinterpret_cast<const short8*>(&As[wm + i * 16 + l15][ks * 32 + quad * 8]);
            #pragma unroll
            for (int j = 0; j < 4; j++)
                bfr[j] = *reinterpret_cast<const short8*>(&Bs[wn + j * 16 + l15][ks * 32 + quad * 8]);
            #pragma unroll
            for (int i = 0; i < 4; i++)
                #pragma unroll
                for (int j = 0; j < 4; j++)
                    acc[i][j] = __builtin_amdgcn_mfma_f32_16x16x32_bf16(af[i], bfr[j], acc[i][j], 0, 0, 0);
        }
    }
}

// ---------------- QKV projection: z selects Wq/Wk/Wv; writes head-major bf16 ----------------
__global__ __launch_bounds__(256) void qkv_gemm_kernel(
        const bf16* __restrict__ xb,
        const bf16* __restrict__ Wqt, const bf16* __restrict__ Wkt, const bf16* __restrict__ Wvt,
        bf16* __restrict__ Qh, bf16* __restrict__ Kh, bf16* __restrict__ Vh) {
    const bf16* Bt; bf16* O; float scale = 1.0f;
    if (blockIdx.z == 0)      { Bt = Wqt; O = Qh; scale = 0.125f; }  // beta = 1/sqrt(64)
    else if (blockIdx.z == 1) { Bt = Wkt; O = Kh; }
    else                      { Bt = Wvt; O = Vh; }
    int n0 = blockIdx.x * 128, m0 = blockIdx.y * 128;
    floatx4 acc[4][4];
    gemm128_body(xb, Bt, m0, n0, acc);

    const int tid = threadIdx.x, wave = tid >> 6, lane = tid & 63;
    const int l15 = lane & 15, quad = lane >> 4;
    const int wm = (wave >> 1) * 64, wn = (wave & 1) * 64;
    #pragma unroll
    for (int i = 0; i < 4; i++)
        #pragma unroll
        for (int j = 0; j < 4; j++) {
            int col = n0 + wn + j * 16 + l15;   // inner index
            int h = col >> 6, d = col & 63;
            #pragma unroll
            for (int r = 0; r < 4; r++) {
                int row = m0 + wm + i * 16 + quad * 4 + r;  // C/D: row = quad*4+reg
                O[((size_t)h * SEQ + row) * DHEAD + d] = __float2bfloat16(acc[i][j][r] * scale);
            }
        }
}

// ---------------- output projection: out = Oa @ Wo + bo (fp32 out) ----------------
__global__ __launch_bounds__(256) void out_gemm_kernel(
        const bf16* __restrict__ Oa, const bf16* __restrict__ Wot,
        const float* __restrict__ bo, float* __restrict__ out) {
    int n0 = blockIdx.x * 128, m0 = blockIdx.y * 128;
    floatx4 acc[4][4];
    gemm128_body(Oa, Wot, m0, n0, acc);

    const int tid = threadIdx.x, wave = tid >> 6, lane = tid & 63;
    const int l15 = lane & 15, quad = lane >> 4;
    const int wm = (wave >> 1) * 64, wn = (wave & 1) * 64;
    #pragma unroll
    for (int i = 0; i < 4; i++)
        #pragma unroll
        for (int j = 0; j < 4; j++) {
            int col = n0 + wn + j * 16 + l15;
            float b = bo[col];
            #pragma unroll
            for (int r = 0; r < 4; r++) {
                int row = m0 + wm + i * 16 + quad * 4 + r;
                out[(size_t)row * DIM + col] = acc[i][j][r] + b;
            }
        }
}

// ---------------- causal flash attention ----------------
// 1 block = 1 head x 64 q-rows; key tile BK=128; V pre-transposed (Vt[h][d][seq]).
// blockIdx.x reversed (qt = 63 - x) so heavy (long-key) blocks dispatch first.
__global__ __launch_bounds__(256) void attention_kernel(
        const bf16* __restrict__ Qh, const bf16* __restrict__ Kh,
        const bf16* __restrict__ Vt, bf16* __restrict__ Oa) {
    __shared__ __align__(16) bf16 Ks[128][72];      // [key][d]
    __shared__ __align__(16) bf16 Vts[64][136];     // [d][key]
    __shared__ __align__(16) bf16 Ps[4][16][136];   // per-wave P: [q][key]
    const int tid = threadIdx.x, wave = tid >> 6, lane = tid & 63;
    const int l15 = lane & 15, quad = lane >> 4;
    const int head = blockIdx.y;
    const int qt = 63 - blockIdx.x;                 // reversed: heavy first
    const int qbase = qt * 64;
    const size_t headoff = (size_t)head * SEQ * DHEAD;
    const bf16* Kb = Kh + headoff;
    const bf16* Vb = Vt + headoff;   // [d][seq] within head

    // Q A-fragments (beta already folded): row = lane&15, k along d
    const int qr = qbase + wave * 16 + l15;
    short8 aq[2];
    #pragma unroll
    for (int s = 0; s < 2; s++)
        aq[s] = *reinterpret_cast<const short8*>(Qh + headoff + (size_t)qr * DHEAD + s * 32 + quad * 8);

    floatx4 acc_o[4];
    #pragma unroll
    for (int c = 0; c < 4; c++) acc_o[c] = (floatx4){0.f, 0.f, 0.f, 0.f};
    float m_run[4], l_run[4];
    #pragma unroll
    for (int r = 0; r < 4; r++) { m_run[r] = -1e30f; l_run[r] = 0.f; }

    const float LOG2E = 1.4426950408889634f;
    const int ntiles = (qbase + 64 + 127) >> 7;     // keys 0..qbase+63, BK=128
    for (int kt = 0; kt < ntiles; kt++) {
        const int kbase = kt * 128;
        __syncthreads();   // protect Ks/Vts from previous-iter readers
        #pragma unroll
        for (int r = 0; r < 4; r++) {
            int u = tid + 256 * r;
            // K tile: 128 keys x 64 d, 16B units along d
            int dg = u & 7, key = u >> 3;
            *reinterpret_cast<short8*>(&Ks[key][dg * 8]) =
                *reinterpret_cast<const short8*>(Kb + (size_t)(kbase + key) * DHEAD + dg * 8);
            // V tile: 64 d x 128 keys, 16B units along seq (pre-transposed!)
            int kg = u & 15, d = u >> 4;
            *reinterpret_cast<short8*>(&Vts[d][kg * 8]) =
                *reinterpret_cast<const short8*>(Vb + (size_t)d * SEQ + kbase + kg * 8);
        }
        __syncthreads();

        // S = Q K^T  (16q x 128key per wave)
        floatx4 acc_s[8];
        #pragma unroll
        for (int c = 0; c < 8; c++) acc_s[c] = (floatx4){0.f, 0.f, 0.f, 0.f};
        #pragma unroll
        for (int c = 0; c < 8; c++)
            #pragma unroll
            for (int s = 0; s < 2; s++) {
                short8 bk = *reinterpret_cast<const short8*>(&Ks[c * 16 + l15][s * 32 + quad * 8]);
                acc_s[c] = __builtin_amdgcn_mfma_f32_16x16x32_bf16(aq[s], bk, acc_s[c], 0, 0, 0);
            }
        // causal mask — wave-uniform skip for fully-unmasked tiles
        if (kbase + 127 > qbase + wave * 16) {
            #pragma unroll
            for (int c = 0; c < 8; c++) {
                int kj = kbase + c * 16 + l15;
                #pragma unroll
                for (int r = 0; r < 4; r++) {
                    int qi = qbase + wave * 16 + quad * 4 + r;
                    if (kj > qi) acc_s[c][r] = -1e30f;
                }
            }
        }
        // online softmax per q-row (16 lanes per row); exp written back into acc_s
        #pragma unroll
        for (int r = 0; r < 4; r++) {
            float mx = acc_s[0][r];
            #pragma unroll
            for (int c = 1; c < 8; c++) mx = fmaxf(mx, acc_s[c][r]);
            #pragma unroll
            for (int off = 1; off < 16; off <<= 1)
                mx = fmaxf(mx, __shfl_xor(mx, off, 16));
            float mnew = fmaxf(m_run[r], mx);
            float alpha = exp2f((m_run[r] - mnew) * LOG2E);
            m_run[r] = mnew;
            float rs = 0.f;
            #pragma unroll
            for (int c = 0; c < 8; c++) {
                float pv = exp2f((acc_s[c][r] - mnew) * LOG2E);
                acc_s[c][r] = pv;
                rs += pv;
            }
            #pragma unroll
            for (int off = 1; off < 16; off <<= 1)
                rs += __shfl_xor(rs, off, 16);
            l_run[r] = l_run[r] * alpha + rs;
            #pragma unroll
            for (int c = 0; c < 4; c++) acc_o[c][r] *= alpha;
        }
        // P: C/D layout -> LDS -> A-operand layout
        #pragma unroll
        for (int c = 0; c < 8; c++)
            #pragma unroll
            for (int r = 0; r < 4; r++)
                Ps[wave][quad * 4 + r][c * 16 + l15] = __float2bfloat16(acc_s[c][r]);
        __syncthreads();
        // O += P V   (16q x 64d, K=128)
        #pragma unroll
        for (int c = 0; c < 4; c++)
            #pragma unroll
            for (int s = 0; s < 4; s++) {
                short8 ap = *reinterpret_cast<const short8*>(&Ps[wave][l15][s * 32 + quad * 8]);
                short8 bv = *reinterpret_cast<const short8*>(&Vts[c * 16 + l15][s * 32 + quad * 8]);
                acc_o[c] = __builtin_amdgcn_mfma_f32_16x16x32_bf16(ap, bv, acc_o[c], 0, 0, 0);
            }
    }
    // write O (row-major [SEQ][INNER] bf16), normalized
    #pragma unroll
    for (int c = 0; c < 4; c++) {
        int col = head * DHEAD + c * 16 + l15;
        #pragma unroll
        for (int r = 0; r < 4; r++) {
            int qi = qbase + wave * 16 + quad * 4 + r;
            Oa[(size_t)qi * INNER + col] = __float2bfloat16(acc_o[c][r] / l_run[r]);
        }
    }
}

extern "C" void kernel_launch(void* const* d_in, const int* in_sizes, int n_in,
                              void* d_out, int out_size, void* d_ws, size_t ws_size,
                              hipStream_t stream) {
    const float* x  = (const float*)d_in[0];
    const float* Wq = (const float*)d_in[1];
    const float* Wk = (const float*)d_in[2];
    const float* Wv = (const float*)d_in[3];
    const float* Wo = (const float*)d_in[4];
    const float* bo = (const float*)d_in[5];
    float* out = (float*)d_out;

    char* ws = (char*)d_ws;
    size_t off = 0;
    bf16* xb  = (bf16*)(ws + off); off += (size_t)SEQ * DIM * 2;
    bf16* Wqt = (bf16*)(ws + off); off += (size_t)DIM * INNER * 2;
    bf16* Wkt = (bf16*)(ws + off); off += (size_t)DIM * INNER * 2;
    bf16* Wvt = (bf16*)(ws + off); off += (size_t)DIM * INNER * 2;
    bf16* Wot = (bf16*)(ws + off); off += (size_t)INNER * DIM * 2;
    bf16* Qh  = (bf16*)(ws + off); off += (size_t)NHEADS * SEQ * DHEAD * 2;
    bf16* Kh  = (bf16*)(ws + off); off += (size_t)NHEADS * SEQ * DHEAD * 2;
    bf16* Vh  = (bf16*)(ws + off); off += (size_t)NHEADS * SEQ * DHEAD * 2;
    bf16* Vtr = (bf16*)(ws + off); off += (size_t)NHEADS * DHEAD * SEQ * 2;
    bf16* Oa  = (bf16*)(ws + off); off += (size_t)SEQ * INNER * 2;  // ~56 MB total

    convert_x_kernel<<<(SEQ * DIM) / 1024, 256, 0, stream>>>(x, xb);
    transpose_w_kernel<<<dim3(32, 32, 4), dim3(32, 8), 0, stream>>>(Wq, Wk, Wv, Wo,
                                                                    Wqt, Wkt, Wvt, Wot);
    qkv_gemm_kernel<<<dim3(8, 32, 3), 256, 0, stream>>>(xb, Wqt, Wkt, Wvt, Qh, Kh, Vh);
    transpose_v_kernel<<<dim3(SEQ / 32, DHEAD / 32, NHEADS), dim3(32, 8), 0, stream>>>(Vh, Vtr);
    attention_kernel<<<dim3(64, 16), 256, 0, stream>>>(Qh, Kh, Vtr, Oa);
    out_gemm_kernel<<<dim3(8, 32), 256, 0, stream>>>(Oa, Wot, bo, out);
}